// Round 18
// baseline (177.217 us; speedup 1.0000x reference)
//
#include <hip/hip_runtime.h>

#define NB 128        // partition blocks for the graph build
#define NWMAX 16384   // max packed words (n <= 65532); n=50000 -> NW=12500
#define LSTR 72       // LDS row stride in shorts (144 B: 16B-aligned, 2-way banks)

typedef __attribute__((ext_vector_type(8))) short bf16x8;
typedef __attribute__((ext_vector_type(4))) float f32x4;

// bf16 round-to-nearest-even helpers
__device__ __forceinline__ unsigned bfr(float x) {
    unsigned u = __float_as_uint(x);
    return (u + 0x7FFFu + ((u >> 16) & 1u)) >> 16;
}
__device__ __forceinline__ unsigned pack2(float lo, float hi) {
    return bfr(lo) | (bfr(hi) << 16);
}
__device__ __forceinline__ float ubf_lo(unsigned q) { return __uint_as_float(q << 16); }
__device__ __forceinline__ float ubf_hi(unsigned q) { return __uint_as_float(q & 0xFFFF0000u); }

// ---------------- graph build ----------------

__global__ void __launch_bounds__(256) k_hist(const int* __restrict__ ei, int E, int chunk,
                                              int NW, unsigned* __restrict__ partialS,
                                              unsigned* __restrict__ partialD) {
    __shared__ unsigned lS[NWMAX];
    __shared__ unsigned lD[NWMAX];
    for (int w = threadIdx.x; w < NW; w += 256) { lS[w] = 0u; lD[w] = 0u; }
    __syncthreads();
    int e0 = blockIdx.x * chunk;
    int e1 = e0 + chunk; if (e1 > E) e1 = E;
    for (int e = e0 + threadIdx.x; e < e1; e += 256) {
        int s = ei[e], d = ei[E + e];
        atomicAdd(&lS[s >> 2], 1u << ((s & 3) * 8));
        atomicAdd(&lD[d >> 2], 1u << ((d & 3) * 8));
    }
    __syncthreads();
    unsigned* pS = partialS + (size_t)blockIdx.x * NW;
    unsigned* pD = partialD + (size_t)blockIdx.x * NW;
    for (int w = threadIdx.x; w < NW; w += 256) { pS[w] = lS[w]; pD[w] = lD[w]; }
}

// Per word (4 nodes): deg -> dis; cnt; per-block exclusive base bytes.
// Pads each slot list to a multiple of 4 with src = n (the zero row).
__global__ void __launch_bounds__(256) k_red(const unsigned* __restrict__ partialS,
                                             const unsigned* __restrict__ partialD,
                                             unsigned* __restrict__ baseM, int NW, int n,
                                             float* __restrict__ dis,
                                             unsigned* __restrict__ cnt,
                                             ushort* __restrict__ slot, int CAP) {
    int w = blockIdx.x * 256 + threadIdx.x;
    if (w >= NW) return;
    unsigned s0 = 0, s1 = 0, s2 = 0, s3 = 0;
    unsigned c0 = 0, c1 = 0, c2 = 0, c3 = 0;
#pragma unroll 8
    for (int b = 0; b < NB; b++) {
        unsigned vs = partialS[(size_t)b * NW + w];
        unsigned vd = partialD[(size_t)b * NW + w];
        baseM[(size_t)b * NW + w] = c0 | (c1 << 8) | (c2 << 16) | (c3 << 24);
        s0 += vs & 0xFF; s1 += (vs >> 8) & 0xFF; s2 += (vs >> 16) & 0xFF; s3 += vs >> 24;
        c0 += vd & 0xFF; c1 += (vd >> 8) & 0xFF; c2 += (vd >> 16) & 0xFF; c3 += vd >> 24;
    }
    unsigned ss[4] = {s0, s1, s2, s3}, cc[4] = {c0, c1, c2, c3};
    int node0 = w * 4;
    if (node0 + 3 < n) {
        ((float4*)dis)[w] = make_float4(s0 ? 1.0f / sqrtf((float)s0) : 0.0f,
                                        s1 ? 1.0f / sqrtf((float)s1) : 0.0f,
                                        s2 ? 1.0f / sqrtf((float)s2) : 0.0f,
                                        s3 ? 1.0f / sqrtf((float)s3) : 0.0f);
        ((uint4*)cnt)[w] = make_uint4(c0, c1, c2, c3);
    } else {
        for (int j = 0; j < 4 && node0 + j < n; j++) {
            dis[node0 + j] = ss[j] ? 1.0f / sqrtf((float)ss[j]) : 0.0f;
            cnt[node0 + j] = cc[j];
        }
    }
#pragma unroll
    for (int j = 0; j < 4; j++) {
        int node = node0 + j;
        if (node >= n) break;
        int c = (int)cc[j]; if (c > CAP) c = CAP;
        int c4 = (c + 3) & ~3; if (c4 > CAP) c4 = CAP;
        for (int e = c; e < c4; e++) slot[(size_t)node * CAP + e] = (ushort)n;
    }
}

// blocks [0,NB): bucket-scatter; blocks [NB,..): grid-stride setup.
// g tables: ROW-MAJOR 128 B rows (n+1 rows incl. zero pad row) — full-line
// gathers; round-14's 64 B half-rows doubled LLC line traffic (reverted).
__global__ void __launch_bounds__(256) k_build3(const int* __restrict__ ei, int E, int chunk,
                                                int NW, const unsigned* __restrict__ baseM,
                                                ushort* __restrict__ slot, int CAP,
                                                const float* __restrict__ x,
                                                const float* __restrict__ dis,
                                                uint2* __restrict__ g0,
                                                uint2* __restrict__ g1,
                                                uint2* __restrict__ xb0,
                                                const float* __restrict__ W1,
                                                const float* __restrict__ W2,
                                                const float* __restrict__ W3,
                                                ushort* __restrict__ Wb, int n) {
    __shared__ unsigned cur[NWMAX];
    __shared__ unsigned bs[NWMAX];
    if ((int)blockIdx.x < NB) {  // ---- scatter part ----
        const unsigned* bRow = baseM + (size_t)blockIdx.x * NW;
        for (int w = threadIdx.x; w < NW; w += 256) { cur[w] = 0u; bs[w] = bRow[w]; }
        __syncthreads();
        int e0 = blockIdx.x * chunk;
        int e1 = e0 + chunk; if (e1 > E) e1 = E;
        for (int e = e0 + threadIdx.x; e < e1; e += 256) {
            int s = ei[e], d = ei[E + e];
            int w = d >> 2, sh = (d & 3) * 8;
            unsigned rank = (atomicAdd(&cur[w], 1u << sh) >> sh) & 0xFF;
            unsigned pos = ((bs[w] >> sh) & 0xFF) + rank;
            if (pos < (unsigned)CAP) slot[(size_t)d * CAP + pos] = (ushort)s;
        }
        return;
    }
    // ---- setup part (grid-stride) ----
    int nblk = gridDim.x - NB;
    int bid = (int)blockIdx.x - NB;
    int tot = (n + 1) * 16;
    for (int i = bid * 256 + threadIdx.x; i < tot; i += nblk * 256) {
        if (i >= n * 16) {  // pad row n: zero in both gather sources
            g0[i] = make_uint2(0u, 0u);
            g1[i] = make_uint2(0u, 0u);
            continue;
        }
        int node = i >> 4;
        float s = dis[node];
        float4 v = ((const float4*)x)[i];
        xb0[i] = make_uint2(pack2(v.x, v.y), pack2(v.z, v.w));
        g0[i]  = make_uint2(pack2(s * v.x, s * v.y), pack2(s * v.z, s * v.w));
    }
    for (int idx = bid * 256 + threadIdx.x; idx < (24 + 24 + 12) * 64; idx += nblk * 256) {
        const float* W; int OUTC, NCT, f; ushort* dst; int id = idx;
        if (id < 24 * 64)      { W = W1; OUTC = 64; NCT = 4; dst = Wb;            f = id >> 6; }
        else if (id < 48 * 64) { W = W2; OUTC = 64; NCT = 4; dst = Wb + 24 * 512; f = (id >> 6) - 24; }
        else                   { W = W3; OUTC = 32; NCT = 2; dst = Wb + 48 * 512; f = (id >> 6) - 48; }
        int l = id & 63;
        int ks = f / NCT, ct = f - ks * NCT;
        int col = ct * 16 + (l & 15);
        int k0 = ks * 32 + (l >> 4) * 8;
        unsigned pk[4];
        for (int jj = 0; jj < 4; jj++) {
            unsigned lohi[2];
            for (int h = 0; h < 2; h++) {
                int k = k0 + jj * 2 + h;
                int seg = k >> 6, r = k & 63;
                float v;
                if (seg == 0)      v = W[r * OUTC + col] - W[(128 + r) * OUTC + col];
                else if (seg == 1) v = W[(64 + r) * OUTC + col];
                else               v = 2.0f * W[(128 + r) * OUTC + col];
                lohi[h] = bfr(v);
            }
            pk[jj] = lohi[0] | (lohi[1] << 16);
        }
        *(uint4*)(dst + ((size_t)f * 64 + l) * 8) = make_uint4(pk[0], pk[1], pk[2], pk[3]);
    }
}

// ---------------- gather core (8 lanes/node, uint4 = 8 bf16 feats/lane) ----------------

struct Acc8 { float a0, a1, a2, a3, a4, a5, a6, a7; };

__device__ __forceinline__ void acc8(Acc8& A, uint4 v) {
    A.a0 += ubf_lo(v.x); A.a1 += ubf_hi(v.x);
    A.a2 += ubf_lo(v.y); A.a3 += ubf_hi(v.y);
    A.a4 += ubf_lo(v.z); A.a5 += ubf_hi(v.z);
    A.a6 += ubf_lo(v.w); A.a7 += ubf_hi(v.w);
}

// 16-edge main step: 2 uint4 index loads + 16 gathers issued before any
// consumption (2x the in-flight VMEM of the round-13 8-edge loop — typical
// node deg~16 is exactly ONE step). Accumulation order identical to two
// sequential 8-steps -> bit-identical output.
__device__ __forceinline__ Acc8 gather_sum(const uint4* __restrict__ gsrc,
                                           const ushort* __restrict__ base, int m4, int j) {
    Acc8 A = {0.f, 0.f, 0.f, 0.f, 0.f, 0.f, 0.f, 0.f};
    int e = 0;
    for (; e + 16 <= m4; e += 16) {
        uint4 qa = *(const uint4*)(base + e);       // 8 u16 indices
        uint4 qb = *(const uint4*)(base + e + 8);   // 8 more
        uint4 v0 = gsrc[(size_t)(qa.x & 0xFFFFu) * 8 + j];
        uint4 v1 = gsrc[(size_t)(qa.x >> 16) * 8 + j];
        uint4 v2 = gsrc[(size_t)(qa.y & 0xFFFFu) * 8 + j];
        uint4 v3 = gsrc[(size_t)(qa.y >> 16) * 8 + j];
        uint4 v4 = gsrc[(size_t)(qa.z & 0xFFFFu) * 8 + j];
        uint4 v5 = gsrc[(size_t)(qa.z >> 16) * 8 + j];
        uint4 v6 = gsrc[(size_t)(qa.w & 0xFFFFu) * 8 + j];
        uint4 v7 = gsrc[(size_t)(qa.w >> 16) * 8 + j];
        uint4 v8 = gsrc[(size_t)(qb.x & 0xFFFFu) * 8 + j];
        uint4 v9 = gsrc[(size_t)(qb.x >> 16) * 8 + j];
        uint4 vA = gsrc[(size_t)(qb.y & 0xFFFFu) * 8 + j];
        uint4 vB = gsrc[(size_t)(qb.y >> 16) * 8 + j];
        uint4 vC = gsrc[(size_t)(qb.z & 0xFFFFu) * 8 + j];
        uint4 vD = gsrc[(size_t)(qb.z >> 16) * 8 + j];
        uint4 vE = gsrc[(size_t)(qb.w & 0xFFFFu) * 8 + j];
        uint4 vF = gsrc[(size_t)(qb.w >> 16) * 8 + j];
        acc8(A, v0); acc8(A, v1); acc8(A, v2); acc8(A, v3);
        acc8(A, v4); acc8(A, v5); acc8(A, v6); acc8(A, v7);
        acc8(A, v8); acc8(A, v9); acc8(A, vA); acc8(A, vB);
        acc8(A, vC); acc8(A, vD); acc8(A, vE); acc8(A, vF);
    }
    if (e + 8 <= m4) {
        uint4 q = *(const uint4*)(base + e);
        uint4 v0 = gsrc[(size_t)(q.x & 0xFFFFu) * 8 + j];
        uint4 v1 = gsrc[(size_t)(q.x >> 16) * 8 + j];
        uint4 v2 = gsrc[(size_t)(q.y & 0xFFFFu) * 8 + j];
        uint4 v3 = gsrc[(size_t)(q.y >> 16) * 8 + j];
        uint4 v4 = gsrc[(size_t)(q.z & 0xFFFFu) * 8 + j];
        uint4 v5 = gsrc[(size_t)(q.z >> 16) * 8 + j];
        uint4 v6 = gsrc[(size_t)(q.w & 0xFFFFu) * 8 + j];
        uint4 v7 = gsrc[(size_t)(q.w >> 16) * 8 + j];
        acc8(A, v0); acc8(A, v1); acc8(A, v2); acc8(A, v3);
        acc8(A, v4); acc8(A, v5); acc8(A, v6); acc8(A, v7);
        e += 8;
    }
    if (e < m4) {  // exactly 4 remain (lists padded to x4)
        uint2 qa = *(const uint2*)(base + e);
        uint4 v0 = gsrc[(size_t)(qa.x & 0xFFFFu) * 8 + j];
        uint4 v1 = gsrc[(size_t)(qa.x >> 16) * 8 + j];
        uint4 v2 = gsrc[(size_t)(qa.y & 0xFFFFu) * 8 + j];
        uint4 v3 = gsrc[(size_t)(qa.y >> 16) * 8 + j];
        acc8(A, v0); acc8(A, v1); acc8(A, v2); acc8(A, v3);
    }
    return A;
}

// ---------------- standalone prop (P1 of each layer): writes xbA + g1 ----------------

__global__ void __launch_bounds__(256) k_prop(const uint4* __restrict__ gsrc,
                                              const unsigned* __restrict__ cnt,
                                              const ushort* __restrict__ slot,
                                              const float* __restrict__ dis,
                                              uint4* __restrict__ xbout,
                                              uint4* __restrict__ gout, int n, int CAP) {
    const int j = threadIdx.x & 7;
    const int node = blockIdx.x * 32 + (threadIdx.x >> 3);
    if (node >= n) return;
    int m = (int)cnt[node]; if (m > CAP) m = CAP;
    int m4 = (m + 3) & ~3;  if (m4 > CAP) m4 = CAP;
    Acc8 A = gather_sum(gsrc, slot + (size_t)node * CAP, m4, j);
    float s = dis[node];
    float f0 = -s * A.a0, f1 = -s * A.a1, f2 = -s * A.a2, f3 = -s * A.a3;
    float f4 = -s * A.a4, f5 = -s * A.a5, f6 = -s * A.a6, f7 = -s * A.a7;
    xbout[(size_t)node * 8 + j] =
        make_uint4(pack2(f0, f1), pack2(f2, f3), pack2(f4, f5), pack2(f6, f7));
    gout[(size_t)node * 8 + j] =
        make_uint4(pack2(s * f0, s * f1), pack2(s * f2, s * f3),
                   pack2(s * f4, s * f5), pack2(s * f6, s * f7));
}

// ---------------- fused prop2 + MFMA GEMM ----------------
// Phase 1: 256 thr = 32 nodes x 8 lanes compute P2 rows -> LDS (bf16, stride 72).
// Phase 2: wave wv (< NCT) computes 32 rows x 16 cols (col-tile wv) via MFMA;
//          K-segments: X0, X1 from global bf16; P2 from LDS.
template <int NCT, bool RELU, bool WG>
__global__ void __launch_bounds__(256) k_pm(const uint4* __restrict__ gsrc,
                                            const unsigned* __restrict__ cnt,
                                            const ushort* __restrict__ slot,
                                            const float* __restrict__ dis,
                                            const ushort* __restrict__ X0,
                                            const ushort* __restrict__ X1,
                                            const ushort* __restrict__ Wb,
                                            const float* __restrict__ bias,
                                            float* __restrict__ outf,
                                            ushort* __restrict__ xbout,
                                            ushort* __restrict__ gout, int n, int CAP) {
    constexpr int OUTC = NCT * 16;
    __shared__ ushort P2[32 * LSTR];
    const int r0 = blockIdx.x * 32;

    {   // phase 1
        const int j = threadIdx.x & 7;
        const int ni = threadIdx.x >> 3;   // 0..31
        const int node = r0 + ni;
        uint4 pk = make_uint4(0u, 0u, 0u, 0u);
        if (node < n) {
            int m = (int)cnt[node]; if (m > CAP) m = CAP;
            int m4 = (m + 3) & ~3;  if (m4 > CAP) m4 = CAP;
            Acc8 A = gather_sum(gsrc, slot + (size_t)node * CAP, m4, j);
            float s = dis[node];
            pk = make_uint4(pack2(-s * A.a0, -s * A.a1), pack2(-s * A.a2, -s * A.a3),
                            pack2(-s * A.a4, -s * A.a5), pack2(-s * A.a6, -s * A.a7));
        }
        *(uint4*)&P2[ni * LSTR + j * 8] = pk;
    }
    __syncthreads();

    const int wv = threadIdx.x >> 6;
    if (wv >= NCT) return;
    const int ct = wv;
    const int l = threadIdx.x & 63;
    const int lm = l & 15, lh = l >> 4, koff = lh * 8;
    const int rA0 = (r0 + lm < n) ? r0 + lm : n - 1;
    const int rA1 = (r0 + 16 + lm < n) ? r0 + 16 + lm : n - 1;

    float bv = bias[ct * 16 + lm];
    f32x4 c0 = {bv, bv, bv, bv}, c1 = c0;

#pragma unroll
    for (int kt = 0; kt < 2; kt++) {  // seg X0: ks 0,1
        bf16x8 a0 = *(const bf16x8*)(X0 + (size_t)rA0 * 64 + kt * 32 + koff);
        bf16x8 a1 = *(const bf16x8*)(X0 + (size_t)rA1 * 64 + kt * 32 + koff);
        bf16x8 b = *(const bf16x8*)(Wb + ((size_t)(kt * NCT + ct) * 64 + l) * 8);
        c0 = __builtin_amdgcn_mfma_f32_16x16x32_bf16(a0, b, c0, 0, 0, 0);
        c1 = __builtin_amdgcn_mfma_f32_16x16x32_bf16(a1, b, c1, 0, 0, 0);
    }
#pragma unroll
    for (int kt = 0; kt < 2; kt++) {  // seg X1: ks 2,3
        bf16x8 a0 = *(const bf16x8*)(X1 + (size_t)rA0 * 64 + kt * 32 + koff);
        bf16x8 a1 = *(const bf16x8*)(X1 + (size_t)rA1 * 64 + kt * 32 + koff);
        bf16x8 b = *(const bf16x8*)(Wb + ((size_t)((2 + kt) * NCT + ct) * 64 + l) * 8);
        c0 = __builtin_amdgcn_mfma_f32_16x16x32_bf16(a0, b, c0, 0, 0, 0);
        c1 = __builtin_amdgcn_mfma_f32_16x16x32_bf16(a1, b, c1, 0, 0, 0);
    }
#pragma unroll
    for (int kt = 0; kt < 2; kt++) {  // seg P2 (LDS): ks 4,5
        bf16x8 a0 = *(const bf16x8*)&P2[lm * LSTR + kt * 32 + koff];
        bf16x8 a1 = *(const bf16x8*)&P2[(16 + lm) * LSTR + kt * 32 + koff];
        bf16x8 b = *(const bf16x8*)(Wb + ((size_t)((4 + kt) * NCT + ct) * 64 + l) * 8);
        c0 = __builtin_amdgcn_mfma_f32_16x16x32_bf16(a0, b, c0, 0, 0, 0);
        c1 = __builtin_amdgcn_mfma_f32_16x16x32_bf16(a1, b, c1, 0, 0, 0);
    }

#pragma unroll
    for (int half = 0; half < 2; half++) {
        int rbase = r0 + half * 16 + lh * 4;
        int col = ct * 16 + lm;
#pragma unroll
        for (int r = 0; r < 4; r++) {
            int row = rbase + r;
            if (row < n) {
                float v = half ? c1[r] : c0[r];
                if (RELU) v = fmaxf(v, 0.0f);
                if (WG) {
                    float s = dis[row];
                    xbout[(size_t)row * OUTC + col] = (ushort)bfr(v);
                    gout[(size_t)row * OUTC + col] = (ushort)bfr(s * v);
                } else {
                    outf[(size_t)row * OUTC + col] = v;
                }
            }
        }
    }
}

// ---------------- launcher ----------------

extern "C" void kernel_launch(void* const* d_in, const int* in_sizes, int n_in,
                              void* d_out, int out_size, void* d_ws, size_t ws_size,
                              hipStream_t stream) {
    const float* x  = (const float*)d_in[0];
    const int*   ei = (const int*)d_in[1];
    const float* W1 = (const float*)d_in[2];
    const float* b1 = (const float*)d_in[3];
    const float* W2 = (const float*)d_in[4];
    const float* b2 = (const float*)d_in[5];
    const float* W3 = (const float*)d_in[6];
    const float* b3 = (const float*)d_in[7];
    float* out = (float*)d_out;

    const int n = in_sizes[0] / 64;
    const int E = in_sizes[1] / 2;
    const int NW = (n + 3) >> 2;
    const int chunk = (E + NB - 1) / NB;

    char* wsp = (char*)d_ws;
    size_t off = 0;
    auto alloc = [&](size_t bytes) -> char* {
        char* p = wsp + off;
        off += (bytes + 255) & ~(size_t)255;
        return p;
    };
    float* dis     = (float*)alloc((size_t)n * 4);
    unsigned* cnt  = (unsigned*)alloc((size_t)n * 4);
    const size_t XB  = (size_t)n * 64 * 2;        // bf16 feature buffer
    const size_t XBP = (size_t)(n + 1) * 64 * 2;  // +1 zero pad row (gather sources)
    ushort* xb0 = (ushort*)alloc(XB);
    ushort* xbA = (ushort*)alloc(XB);
    ushort* xbC = (ushort*)alloc(XB);
    ushort* xbD = (ushort*)alloc(XB);
    ushort* g0  = (ushort*)alloc(XBP);
    ushort* g1  = (ushort*)alloc(XBP);
    ushort* Wb  = (ushort*)alloc((size_t)60 * 512 * 2);

    // build temporaries alias bf16 buffers (each NB*NW*4 = 6.4 MB = XB):
    // baseM over xbA; partialS over xbC; partialD over xbD — all dead before
    // their aliased buffers are first written.
    unsigned* baseM    = (unsigned*)xbA;
    unsigned* partialS = (unsigned*)xbC;
    unsigned* partialD = (unsigned*)xbD;

    size_t leftover = (ws_size > off) ? (ws_size - off) : 0;
    int CAP = (int)(leftover / ((size_t)n * 2));
    if (CAP > 64) CAP = 64;
    if (CAP < 16) CAP = 16;
    CAP &= ~7;  // multiple of 8: 16B-aligned uint4 index loads
    ushort* slot = (ushort*)alloc((size_t)n * CAP * 2);

    const int nb_red  = (NW + 255) / 256;
    const int nb_prop = (n + 31) / 32;

    k_hist<<<NB, 256, 0, stream>>>(ei, E, chunk, NW, partialS, partialD);
    k_red<<<nb_red, 256, 0, stream>>>(partialS, partialD, baseM, NW, n, dis, cnt, slot, CAP);
    k_build3<<<NB + 128, 256, 0, stream>>>(ei, E, chunk, NW, baseM, slot, CAP,
                                           x, dis, (uint2*)g0, (uint2*)g1, (uint2*)xb0,
                                           W1, W2, W3, Wb, n);

    // layer 1: P1 -> (xbA, g1); fused P2+GEMM -> (xbC, g0)
    k_prop<<<nb_prop, 256, 0, stream>>>((uint4*)g0, cnt, slot, dis, (uint4*)xbA,
                                        (uint4*)g1, n, CAP);
    k_pm<4, true, true><<<nb_prop, 256, 0, stream>>>((uint4*)g1, cnt, slot, dis, xb0, xbA,
                                                     Wb, b1, nullptr, xbC, g0, n, CAP);

    // layer 2
    k_prop<<<nb_prop, 256, 0, stream>>>((uint4*)g0, cnt, slot, dis, (uint4*)xbA,
                                        (uint4*)g1, n, CAP);
    k_pm<4, true, true><<<nb_prop, 256, 0, stream>>>((uint4*)g1, cnt, slot, dis, xbC, xbA,
                                                     Wb + 24 * 512, b2, nullptr, xbD, g0,
                                                     n, CAP);

    // layer 3 (32 cols, no relu, f32 out)
    k_prop<<<nb_prop, 256, 0, stream>>>((uint4*)g0, cnt, slot, dis, (uint4*)xbA,
                                        (uint4*)g1, n, CAP);
    k_pm<2, false, false><<<nb_prop, 256, 0, stream>>>((uint4*)g1, cnt, slot, dis, xbD, xbA,
                                                       Wb + 48 * 512, b3, out, nullptr,
                                                       nullptr, n, CAP);
}

// Round 20
// 173.816 us; speedup vs baseline: 1.0196x; 1.0196x over previous
//
#include <hip/hip_runtime.h>

#define NB 128        // partition blocks for the graph build
#define NWMAX 16384   // max packed words (n <= 65532); n=50000 -> NW=12500
#define LSTR 72       // LDS row stride in shorts (144 B: 16B-aligned, 2-way banks)

typedef __attribute__((ext_vector_type(8))) short bf16x8;
typedef __attribute__((ext_vector_type(4))) float f32x4;

// bf16 round-to-nearest-even helpers
__device__ __forceinline__ unsigned bfr(float x) {
    unsigned u = __float_as_uint(x);
    return (u + 0x7FFFu + ((u >> 16) & 1u)) >> 16;
}
__device__ __forceinline__ unsigned pack2(float lo, float hi) {
    return bfr(lo) | (bfr(hi) << 16);
}
__device__ __forceinline__ float ubf_lo(unsigned q) { return __uint_as_float(q << 16); }
__device__ __forceinline__ float ubf_hi(unsigned q) { return __uint_as_float(q & 0xFFFF0000u); }

// ---------------- graph build ----------------

__global__ void __launch_bounds__(256) k_hist(const int* __restrict__ ei, int E, int chunk,
                                              int NW, unsigned* __restrict__ partialS,
                                              unsigned* __restrict__ partialD) {
    __shared__ unsigned lS[NWMAX];
    __shared__ unsigned lD[NWMAX];
    for (int w = threadIdx.x; w < NW; w += 256) { lS[w] = 0u; lD[w] = 0u; }
    __syncthreads();
    int e0 = blockIdx.x * chunk;
    int e1 = e0 + chunk; if (e1 > E) e1 = E;
    for (int e = e0 + threadIdx.x; e < e1; e += 256) {
        int s = ei[e], d = ei[E + e];
        atomicAdd(&lS[s >> 2], 1u << ((s & 3) * 8));
        atomicAdd(&lD[d >> 2], 1u << ((d & 3) * 8));
    }
    __syncthreads();
    unsigned* pS = partialS + (size_t)blockIdx.x * NW;
    unsigned* pD = partialD + (size_t)blockIdx.x * NW;
    for (int w = threadIdx.x; w < NW; w += 256) { pS[w] = lS[w]; pD[w] = lD[w]; }
}

// Per word (4 nodes): deg -> dis; cnt; per-block exclusive base bytes.
// Pads each slot list to a multiple of 4 with src = n (the zero row).
__global__ void __launch_bounds__(256) k_red(const unsigned* __restrict__ partialS,
                                             const unsigned* __restrict__ partialD,
                                             unsigned* __restrict__ baseM, int NW, int n,
                                             float* __restrict__ dis,
                                             unsigned* __restrict__ cnt,
                                             ushort* __restrict__ slot, int CAP) {
    int w = blockIdx.x * 256 + threadIdx.x;
    if (w >= NW) return;
    unsigned s0 = 0, s1 = 0, s2 = 0, s3 = 0;
    unsigned c0 = 0, c1 = 0, c2 = 0, c3 = 0;
#pragma unroll 8
    for (int b = 0; b < NB; b++) {
        unsigned vs = partialS[(size_t)b * NW + w];
        unsigned vd = partialD[(size_t)b * NW + w];
        baseM[(size_t)b * NW + w] = c0 | (c1 << 8) | (c2 << 16) | (c3 << 24);
        s0 += vs & 0xFF; s1 += (vs >> 8) & 0xFF; s2 += (vs >> 16) & 0xFF; s3 += vs >> 24;
        c0 += vd & 0xFF; c1 += (vd >> 8) & 0xFF; c2 += (vd >> 16) & 0xFF; c3 += vd >> 24;
    }
    unsigned ss[4] = {s0, s1, s2, s3}, cc[4] = {c0, c1, c2, c3};
    int node0 = w * 4;
    if (node0 + 3 < n) {
        ((float4*)dis)[w] = make_float4(s0 ? 1.0f / sqrtf((float)s0) : 0.0f,
                                        s1 ? 1.0f / sqrtf((float)s1) : 0.0f,
                                        s2 ? 1.0f / sqrtf((float)s2) : 0.0f,
                                        s3 ? 1.0f / sqrtf((float)s3) : 0.0f);
        ((uint4*)cnt)[w] = make_uint4(c0, c1, c2, c3);
    } else {
        for (int j = 0; j < 4 && node0 + j < n; j++) {
            dis[node0 + j] = ss[j] ? 1.0f / sqrtf((float)ss[j]) : 0.0f;
            cnt[node0 + j] = cc[j];
        }
    }
#pragma unroll
    for (int j = 0; j < 4; j++) {
        int node = node0 + j;
        if (node >= n) break;
        int c = (int)cc[j]; if (c > CAP) c = CAP;
        int c4 = (c + 3) & ~3; if (c4 > CAP) c4 = CAP;
        for (int e = c; e < c4; e++) slot[(size_t)node * CAP + e] = (ushort)n;
    }
}

// blocks [0,NB): bucket-scatter; blocks [NB,..): grid-stride setup.
// g tables: ROW-MAJOR 128 B rows (n+1 rows incl. zero pad row) — full-line
// gathers; round-14's 64 B half-rows doubled LLC line traffic (reverted).
__global__ void __launch_bounds__(256) k_build3(const int* __restrict__ ei, int E, int chunk,
                                                int NW, const unsigned* __restrict__ baseM,
                                                ushort* __restrict__ slot, int CAP,
                                                const float* __restrict__ x,
                                                const float* __restrict__ dis,
                                                uint2* __restrict__ g0,
                                                uint2* __restrict__ g1,
                                                uint2* __restrict__ xb0,
                                                const float* __restrict__ W1,
                                                const float* __restrict__ W2,
                                                const float* __restrict__ W3,
                                                ushort* __restrict__ Wb, int n) {
    __shared__ unsigned cur[NWMAX];
    __shared__ unsigned bs[NWMAX];
    if ((int)blockIdx.x < NB) {  // ---- scatter part ----
        const unsigned* bRow = baseM + (size_t)blockIdx.x * NW;
        for (int w = threadIdx.x; w < NW; w += 256) { cur[w] = 0u; bs[w] = bRow[w]; }
        __syncthreads();
        int e0 = blockIdx.x * chunk;
        int e1 = e0 + chunk; if (e1 > E) e1 = E;
        for (int e = e0 + threadIdx.x; e < e1; e += 256) {
            int s = ei[e], d = ei[E + e];
            int w = d >> 2, sh = (d & 3) * 8;
            unsigned rank = (atomicAdd(&cur[w], 1u << sh) >> sh) & 0xFF;
            unsigned pos = ((bs[w] >> sh) & 0xFF) + rank;
            if (pos < (unsigned)CAP) slot[(size_t)d * CAP + pos] = (ushort)s;
        }
        return;
    }
    // ---- setup part (grid-stride) ----
    int nblk = gridDim.x - NB;
    int bid = (int)blockIdx.x - NB;
    int tot = (n + 1) * 16;
    for (int i = bid * 256 + threadIdx.x; i < tot; i += nblk * 256) {
        if (i >= n * 16) {  // pad row n: zero in both gather sources
            g0[i] = make_uint2(0u, 0u);
            g1[i] = make_uint2(0u, 0u);
            continue;
        }
        int node = i >> 4;
        float s = dis[node];
        float4 v = ((const float4*)x)[i];
        xb0[i] = make_uint2(pack2(v.x, v.y), pack2(v.z, v.w));
        g0[i]  = make_uint2(pack2(s * v.x, s * v.y), pack2(s * v.z, s * v.w));
    }
    for (int idx = bid * 256 + threadIdx.x; idx < (24 + 24 + 12) * 64; idx += nblk * 256) {
        const float* W; int OUTC, NCT, f; ushort* dst; int id = idx;
        if (id < 24 * 64)      { W = W1; OUTC = 64; NCT = 4; dst = Wb;            f = id >> 6; }
        else if (id < 48 * 64) { W = W2; OUTC = 64; NCT = 4; dst = Wb + 24 * 512; f = (id >> 6) - 24; }
        else                   { W = W3; OUTC = 32; NCT = 2; dst = Wb + 48 * 512; f = (id >> 6) - 48; }
        int l = id & 63;
        int ks = f / NCT, ct = f - ks * NCT;
        int col = ct * 16 + (l & 15);
        int k0 = ks * 32 + (l >> 4) * 8;
        unsigned pk[4];
        for (int jj = 0; jj < 4; jj++) {
            unsigned lohi[2];
            for (int h = 0; h < 2; h++) {
                int k = k0 + jj * 2 + h;
                int seg = k >> 6, r = k & 63;
                float v;
                if (seg == 0)      v = W[r * OUTC + col] - W[(128 + r) * OUTC + col];
                else if (seg == 1) v = W[(64 + r) * OUTC + col];
                else               v = 2.0f * W[(128 + r) * OUTC + col];
                lohi[h] = bfr(v);
            }
            pk[jj] = lohi[0] | (lohi[1] << 16);
        }
        *(uint4*)(dst + ((size_t)f * 64 + l) * 8) = make_uint4(pk[0], pk[1], pk[2], pk[3]);
    }
}

// ---------------- gather core (8 lanes/node, uint4 = 8 bf16 feats/lane) ----------------

struct Acc8 { float a0, a1, a2, a3, a4, a5, a6, a7; };

__device__ __forceinline__ void acc8(Acc8& A, uint4 v) {
    A.a0 += ubf_lo(v.x); A.a1 += ubf_hi(v.x);
    A.a2 += ubf_lo(v.y); A.a3 += ubf_hi(v.y);
    A.a4 += ubf_lo(v.z); A.a5 += ubf_hi(v.z);
    A.a6 += ubf_lo(v.w); A.a7 += ubf_hi(v.w);
}

// uint4 index loads: 8 u16 indices per VMEM instruction (CAP multiple of 8).
// All accesses normally cached — round 16 showed nontemporal hints REGRESS
// (slot is re-read by all 6 passes; xbout is read by the very next kernel).
__device__ __forceinline__ Acc8 gather_sum(const uint4* __restrict__ gsrc,
                                           const ushort* __restrict__ base, int m4, int j) {
    Acc8 A = {0.f, 0.f, 0.f, 0.f, 0.f, 0.f, 0.f, 0.f};
    int e = 0;
    for (; e + 8 <= m4; e += 8) {
        uint4 q = *(const uint4*)(base + e);   // 8 u16 indices
        uint4 v0 = gsrc[(size_t)(q.x & 0xFFFFu) * 8 + j];
        uint4 v1 = gsrc[(size_t)(q.x >> 16) * 8 + j];
        uint4 v2 = gsrc[(size_t)(q.y & 0xFFFFu) * 8 + j];
        uint4 v3 = gsrc[(size_t)(q.y >> 16) * 8 + j];
        uint4 v4 = gsrc[(size_t)(q.z & 0xFFFFu) * 8 + j];
        uint4 v5 = gsrc[(size_t)(q.z >> 16) * 8 + j];
        uint4 v6 = gsrc[(size_t)(q.w & 0xFFFFu) * 8 + j];
        uint4 v7 = gsrc[(size_t)(q.w >> 16) * 8 + j];
        acc8(A, v0); acc8(A, v1); acc8(A, v2); acc8(A, v3);
        acc8(A, v4); acc8(A, v5); acc8(A, v6); acc8(A, v7);
    }
    if (e < m4) {  // exactly 4 remain (lists padded to x4)
        uint2 qa = *(const uint2*)(base + e);
        uint4 v0 = gsrc[(size_t)(qa.x & 0xFFFFu) * 8 + j];
        uint4 v1 = gsrc[(size_t)(qa.x >> 16) * 8 + j];
        uint4 v2 = gsrc[(size_t)(qa.y & 0xFFFFu) * 8 + j];
        uint4 v3 = gsrc[(size_t)(qa.y >> 16) * 8 + j];
        acc8(A, v0); acc8(A, v1); acc8(A, v2); acc8(A, v3);
    }
    return A;
}

// ---------------- standalone prop (P1 of each layer): writes xbA + g1 ----------------

__global__ void __launch_bounds__(256) k_prop(const uint4* __restrict__ gsrc,
                                              const unsigned* __restrict__ cnt,
                                              const ushort* __restrict__ slot,
                                              const float* __restrict__ dis,
                                              uint4* __restrict__ xbout,
                                              uint4* __restrict__ gout, int n, int CAP) {
    const int j = threadIdx.x & 7;
    const int node = blockIdx.x * 32 + (threadIdx.x >> 3);
    if (node >= n) return;
    int m = (int)cnt[node]; if (m > CAP) m = CAP;
    int m4 = (m + 3) & ~3;  if (m4 > CAP) m4 = CAP;
    Acc8 A = gather_sum(gsrc, slot + (size_t)node * CAP, m4, j);
    float s = dis[node];
    float f0 = -s * A.a0, f1 = -s * A.a1, f2 = -s * A.a2, f3 = -s * A.a3;
    float f4 = -s * A.a4, f5 = -s * A.a5, f6 = -s * A.a6, f7 = -s * A.a7;
    xbout[(size_t)node * 8 + j] =
        make_uint4(pack2(f0, f1), pack2(f2, f3), pack2(f4, f5), pack2(f6, f7));
    gout[(size_t)node * 8 + j] =
        make_uint4(pack2(s * f0, s * f1), pack2(s * f2, s * f3),
                   pack2(s * f4, s * f5), pack2(s * f6, s * f7));
}

// ---------------- fused prop2 + MFMA GEMM ----------------
// Phase 1: 256 thr = 32 nodes x 8 lanes compute P2 rows -> LDS (bf16, stride 72).
// Phase 2: wave wv (< NCT) computes 32 rows x 16 cols (col-tile wv) via MFMA;
//          K-segments: X0, X1 from global bf16; P2 from LDS.
template <int NCT, bool RELU, bool WG>
__global__ void __launch_bounds__(256) k_pm(const uint4* __restrict__ gsrc,
                                            const unsigned* __restrict__ cnt,
                                            const ushort* __restrict__ slot,
                                            const float* __restrict__ dis,
                                            const ushort* __restrict__ X0,
                                            const ushort* __restrict__ X1,
                                            const ushort* __restrict__ Wb,
                                            const float* __restrict__ bias,
                                            float* __restrict__ outf,
                                            ushort* __restrict__ xbout,
                                            ushort* __restrict__ gout, int n, int CAP) {
    constexpr int OUTC = NCT * 16;
    __shared__ ushort P2[32 * LSTR];
    const int r0 = blockIdx.x * 32;

    {   // phase 1
        const int j = threadIdx.x & 7;
        const int ni = threadIdx.x >> 3;   // 0..31
        const int node = r0 + ni;
        uint4 pk = make_uint4(0u, 0u, 0u, 0u);
        if (node < n) {
            int m = (int)cnt[node]; if (m > CAP) m = CAP;
            int m4 = (m + 3) & ~3;  if (m4 > CAP) m4 = CAP;
            Acc8 A = gather_sum(gsrc, slot + (size_t)node * CAP, m4, j);
            float s = dis[node];
            pk = make_uint4(pack2(-s * A.a0, -s * A.a1), pack2(-s * A.a2, -s * A.a3),
                            pack2(-s * A.a4, -s * A.a5), pack2(-s * A.a6, -s * A.a7));
        }
        *(uint4*)&P2[ni * LSTR + j * 8] = pk;
    }
    __syncthreads();

    const int wv = threadIdx.x >> 6;
    if (wv >= NCT) return;
    const int ct = wv;
    const int l = threadIdx.x & 63;
    const int lm = l & 15, lh = l >> 4, koff = lh * 8;
    const int rA0 = (r0 + lm < n) ? r0 + lm : n - 1;
    const int rA1 = (r0 + 16 + lm < n) ? r0 + 16 + lm : n - 1;

    float bv = bias[ct * 16 + lm];
    f32x4 c0 = {bv, bv, bv, bv}, c1 = c0;

#pragma unroll
    for (int kt = 0; kt < 2; kt++) {  // seg X0: ks 0,1
        bf16x8 a0 = *(const bf16x8*)(X0 + (size_t)rA0 * 64 + kt * 32 + koff);
        bf16x8 a1 = *(const bf16x8*)(X0 + (size_t)rA1 * 64 + kt * 32 + koff);
        bf16x8 b = *(const bf16x8*)(Wb + ((size_t)(kt * NCT + ct) * 64 + l) * 8);
        c0 = __builtin_amdgcn_mfma_f32_16x16x32_bf16(a0, b, c0, 0, 0, 0);
        c1 = __builtin_amdgcn_mfma_f32_16x16x32_bf16(a1, b, c1, 0, 0, 0);
    }
#pragma unroll
    for (int kt = 0; kt < 2; kt++) {  // seg X1: ks 2,3
        bf16x8 a0 = *(const bf16x8*)(X1 + (size_t)rA0 * 64 + kt * 32 + koff);
        bf16x8 a1 = *(const bf16x8*)(X1 + (size_t)rA1 * 64 + kt * 32 + koff);
        bf16x8 b = *(const bf16x8*)(Wb + ((size_t)((2 + kt) * NCT + ct) * 64 + l) * 8);
        c0 = __builtin_amdgcn_mfma_f32_16x16x32_bf16(a0, b, c0, 0, 0, 0);
        c1 = __builtin_amdgcn_mfma_f32_16x16x32_bf16(a1, b, c1, 0, 0, 0);
    }
#pragma unroll
    for (int kt = 0; kt < 2; kt++) {  // seg P2 (LDS): ks 4,5
        bf16x8 a0 = *(const bf16x8*)&P2[lm * LSTR + kt * 32 + koff];
        bf16x8 a1 = *(const bf16x8*)&P2[(16 + lm) * LSTR + kt * 32 + koff];
        bf16x8 b = *(const bf16x8*)(Wb + ((size_t)((4 + kt) * NCT + ct) * 64 + l) * 8);
        c0 = __builtin_amdgcn_mfma_f32_16x16x32_bf16(a0, b, c0, 0, 0, 0);
        c1 = __builtin_amdgcn_mfma_f32_16x16x32_bf16(a1, b, c1, 0, 0, 0);
    }

#pragma unroll
    for (int half = 0; half < 2; half++) {
        int rbase = r0 + half * 16 + lh * 4;
        int col = ct * 16 + lm;
#pragma unroll
        for (int r = 0; r < 4; r++) {
            int row = rbase + r;
            if (row < n) {
                float v = half ? c1[r] : c0[r];
                if (RELU) v = fmaxf(v, 0.0f);
                if (WG) {
                    float s = dis[row];
                    xbout[(size_t)row * OUTC + col] = (ushort)bfr(v);
                    gout[(size_t)row * OUTC + col] = (ushort)bfr(s * v);
                } else {
                    outf[(size_t)row * OUTC + col] = v;
                }
            }
        }
    }
}

// ---------------- launcher ----------------

extern "C" void kernel_launch(void* const* d_in, const int* in_sizes, int n_in,
                              void* d_out, int out_size, void* d_ws, size_t ws_size,
                              hipStream_t stream) {
    const float* x  = (const float*)d_in[0];
    const int*   ei = (const int*)d_in[1];
    const float* W1 = (const float*)d_in[2];
    const float* b1 = (const float*)d_in[3];
    const float* W2 = (const float*)d_in[4];
    const float* b2 = (const float*)d_in[5];
    const float* W3 = (const float*)d_in[6];
    const float* b3 = (const float*)d_in[7];
    float* out = (float*)d_out;

    const int n = in_sizes[0] / 64;
    const int E = in_sizes[1] / 2;
    const int NW = (n + 3) >> 2;
    const int chunk = (E + NB - 1) / NB;

    char* wsp = (char*)d_ws;
    size_t off = 0;
    auto alloc = [&](size_t bytes) -> char* {
        char* p = wsp + off;
        off += (bytes + 255) & ~(size_t)255;
        return p;
    };
    float* dis     = (float*)alloc((size_t)n * 4);
    unsigned* cnt  = (unsigned*)alloc((size_t)n * 4);
    const size_t XB  = (size_t)n * 64 * 2;        // bf16 feature buffer
    const size_t XBP = (size_t)(n + 1) * 64 * 2;  // +1 zero pad row (gather sources)
    ushort* xb0 = (ushort*)alloc(XB);
    ushort* xbA = (ushort*)alloc(XB);
    ushort* xbC = (ushort*)alloc(XB);
    ushort* xbD = (ushort*)alloc(XB);
    ushort* g0  = (ushort*)alloc(XBP);
    ushort* g1  = (ushort*)alloc(XBP);
    ushort* Wb  = (ushort*)alloc((size_t)60 * 512 * 2);

    // build temporaries alias bf16 buffers (each NB*NW*4 = 6.4 MB = XB):
    // baseM over xbA; partialS over xbC; partialD over xbD — all dead before
    // their aliased buffers are first written.
    unsigned* baseM    = (unsigned*)xbA;
    unsigned* partialS = (unsigned*)xbC;
    unsigned* partialD = (unsigned*)xbD;

    size_t leftover = (ws_size > off) ? (ws_size - off) : 0;
    int CAP = (int)(leftover / ((size_t)n * 2));
    if (CAP > 64) CAP = 64;
    if (CAP < 16) CAP = 16;
    CAP &= ~7;  // multiple of 8: 16B-aligned uint4 index loads
    ushort* slot = (ushort*)alloc((size_t)n * CAP * 2);

    const int nb_red  = (NW + 255) / 256;
    const int nb_prop = (n + 31) / 32;

    k_hist<<<NB, 256, 0, stream>>>(ei, E, chunk, NW, partialS, partialD);
    k_red<<<nb_red, 256, 0, stream>>>(partialS, partialD, baseM, NW, n, dis, cnt, slot, CAP);
    k_build3<<<NB + 128, 256, 0, stream>>>(ei, E, chunk, NW, baseM, slot, CAP,
                                           x, dis, (uint2*)g0, (uint2*)g1, (uint2*)xb0,
                                           W1, W2, W3, Wb, n);

    // layer 1: P1 -> (xbA, g1); fused P2+GEMM -> (xbC, g0)
    k_prop<<<nb_prop, 256, 0, stream>>>((uint4*)g0, cnt, slot, dis, (uint4*)xbA,
                                        (uint4*)g1, n, CAP);
    k_pm<4, true, true><<<nb_prop, 256, 0, stream>>>((uint4*)g1, cnt, slot, dis, xb0, xbA,
                                                     Wb, b1, nullptr, xbC, g0, n, CAP);

    // layer 2
    k_prop<<<nb_prop, 256, 0, stream>>>((uint4*)g0, cnt, slot, dis, (uint4*)xbA,
                                        (uint4*)g1, n, CAP);
    k_pm<4, true, true><<<nb_prop, 256, 0, stream>>>((uint4*)g1, cnt, slot, dis, xbC, xbA,
                                                     Wb + 24 * 512, b2, nullptr, xbD, g0,
                                                     n, CAP);

    // layer 3 (32 cols, no relu, f32 out)
    k_prop<<<nb_prop, 256, 0, stream>>>((uint4*)g0, cnt, slot, dis, (uint4*)xbA,
                                        (uint4*)g1, n, CAP);
    k_pm<2, false, false><<<nb_prop, 256, 0, stream>>>((uint4*)g1, cnt, slot, dis, xbD, xbA,
                                                       Wb + 48 * 512, b3, out, nullptr,
                                                       nullptr, n, CAP);
}